// Round 1
// baseline (2746.461 us; speedup 1.0000x reference)
//
#include <hip/hip_runtime.h>
#include <hip/hip_bf16.h>
#include <stdint.h>

#define C_DIM 128
#define K_DIM 27

typedef __attribute__((ext_vector_type(8))) short short8;
typedef __attribute__((ext_vector_type(4))) float f32x4;
typedef __attribute__((ext_vector_type(4))) unsigned short ushort4v;

__device__ __forceinline__ unsigned short f2bf(float f) {
  unsigned int u = __builtin_bit_cast(unsigned int, f);
  u += 0x7fffu + ((u >> 16) & 1u);   // round-to-nearest-even
  return (unsigned short)(u >> 16);
}
__device__ __forceinline__ float bf2f(unsigned short h) {
  unsigned int u = ((unsigned int)h) << 16;
  return __builtin_bit_cast(float, u);
}

// ---- transpose W1,W2 [k][ci][co] f32 -> [k][co][ci] bf16; zero stats ----
__global__ __launch_bounds__(256) void prep_kernel(
    const float* __restrict__ W1, const float* __restrict__ W2,
    unsigned short* __restrict__ Wt1, unsigned short* __restrict__ Wt2,
    float* __restrict__ stats, int stats_n) {
  int idx = blockIdx.x * 256 + threadIdx.x;
  const int total = K_DIM * C_DIM * C_DIM;
  if (idx < total) {
    int k = idx >> 14;          // / (128*128)
    int co = (idx >> 7) & 127;
    int ci = idx & 127;
    int src = (k * C_DIM + ci) * C_DIM + co;
    Wt1[idx] = f2bf(W1[src]);
    Wt2[idx] = f2bf(W2[src]);
  }
  if (idx < stats_n) stats[idx] = 0.f;
}

// ---- x f32 -> bf16 copy ----
__global__ __launch_bounds__(256) void cvt_x_kernel(
    const float* __restrict__ x, unsigned short* __restrict__ xb, int total4) {
  int i = blockIdx.x * 256 + threadIdx.x;
  if (i >= total4) return;
  f32x4 v = ((const f32x4*)x)[i];
  ushort4v u;
#pragma unroll
  for (int j = 0; j < 4; ++j) u[j] = f2bf(v[j]);
  ((ushort4v*)xb)[i] = u;
}

// ---- gathered GEMM: out[i] = sum_k src[nbr[i,k]] @ W[k] ----
// block = 256 thr (4 waves), 32 rows x 128 cols per block.
// wave w owns cols [w*32, w*32+32); 2x2 tiles of 16x16x32 MFMA.
template<int SRC_IS_F32, int OUT_IS_F32>
__global__ __launch_bounds__(256) void conv_kernel(
    const void* __restrict__ src_v, const int* __restrict__ nbr,
    const unsigned short* __restrict__ Wt, void* __restrict__ out_v, int N) {
  const int tid = threadIdx.x;
  const int wave = tid >> 6;
  const int lane = tid & 63;
  const int lr = lane & 15;   // A-row / B-col within 16-tile
  const int lg = lane >> 4;   // k-group 0..3
  const int row0 = blockIdx.x * 32;
  const int wcol = wave * 32;

  const float* xf = (const float*)src_v;
  const unsigned short* xb = (const unsigned short*)src_v;

  f32x4 acc[2][2] = {};

  int m0 = row0 + lr;      if (m0 >= N) m0 = N - 1;
  int m1 = row0 + 16 + lr; if (m1 >= N) m1 = N - 1;

  for (int k = 0; k < K_DIM; ++k) {
    const int n0 = nbr[m0 * K_DIM + k];
    const int n1 = nbr[m1 * K_DIM + k];
    const size_t base0 = (size_t)n0 * C_DIM;
    const size_t base1 = (size_t)n1 * C_DIM;
#pragma unroll
    for (int cb = 0; cb < C_DIM; cb += 32) {
      const int coff = cb + lg * 8;
      short8 a0, a1;
      if (SRC_IS_F32) {
        const f32x4* p0 = (const f32x4*)(xf + base0 + coff);
        const f32x4* p1 = (const f32x4*)(xf + base1 + coff);
        f32x4 v0 = p0[0], v1 = p0[1];
        f32x4 w0 = p1[0], w1 = p1[1];
#pragma unroll
        for (int j = 0; j < 4; ++j) {
          a0[j]     = (short)f2bf(v0[j]);
          a0[j + 4] = (short)f2bf(v1[j]);
          a1[j]     = (short)f2bf(w0[j]);
          a1[j + 4] = (short)f2bf(w1[j]);
        }
      } else {
        a0 = *(const short8*)(xb + base0 + coff);
        a1 = *(const short8*)(xb + base1 + coff);
      }
      const unsigned short* wp =
          Wt + ((size_t)k << 14) + (size_t)(wcol + lr) * C_DIM + coff;
      short8 b0 = *(const short8*)(wp);
      short8 b1 = *(const short8*)(wp + 16 * C_DIM);
      acc[0][0] = __builtin_amdgcn_mfma_f32_16x16x32_bf16(a0, b0, acc[0][0], 0, 0, 0);
      acc[0][1] = __builtin_amdgcn_mfma_f32_16x16x32_bf16(a0, b1, acc[0][1], 0, 0, 0);
      acc[1][0] = __builtin_amdgcn_mfma_f32_16x16x32_bf16(a1, b0, acc[1][0], 0, 0, 0);
      acc[1][1] = __builtin_amdgcn_mfma_f32_16x16x32_bf16(a1, b1, acc[1][1], 0, 0, 0);
    }
  }

  // C/D layout: col = lane&15, row = (lane>>4)*4 + reg  [m89-verified]
#pragma unroll
  for (int r = 0; r < 2; ++r) {
#pragma unroll
    for (int j = 0; j < 4; ++j) {
      int row = row0 + r * 16 + lg * 4 + j;
      if (row >= N) continue;
#pragma unroll
      for (int c = 0; c < 2; ++c) {
        int col = wcol + c * 16 + lr;
        if (OUT_IS_F32)
          ((float*)out_v)[(size_t)row * C_DIM + col] = acc[r][c][j];
        else
          ((unsigned short*)out_v)[(size_t)row * C_DIM + col] = f2bf(acc[r][c][j]);
      }
    }
  }
}

// ---- per-channel sum / sumsq ----
template<int SRC_IS_F32>
__global__ __launch_bounds__(256) void stats_kernel(
    const void* __restrict__ y_v, float* __restrict__ stats, int N) {
  const int tid = threadIdx.x;
  const int c = tid & 127;
  const int half = tid >> 7;
  const float* yf = (const float*)y_v;
  const unsigned short* yb = (const unsigned short*)y_v;
  float s = 0.f, ss = 0.f;
  for (int row = blockIdx.x * 2 + half; row < N; row += gridDim.x * 2) {
    float v = SRC_IS_F32 ? yf[(size_t)row * C_DIM + c]
                         : bf2f(yb[(size_t)row * C_DIM + c]);
    s += v;
    ss += v * v;
  }
  __shared__ float sh_s[128], sh_ss[128];
  if (half == 1) { sh_s[c] = s; sh_ss[c] = ss; }
  __syncthreads();
  if (half == 0) {
    atomicAdd(&stats[c], s + sh_s[c]);
    atomicAdd(&stats[128 + c], ss + sh_ss[c]);
  }
}

// ---- stats -> scale/shift ----
__global__ void finalize_kernel(const float* __restrict__ stats,
                                const float* __restrict__ g,
                                const float* __restrict__ b,
                                float* __restrict__ sshift, float invN) {
  int c = threadIdx.x;  // blockDim = 128
  float mean = stats[c] * invN;
  float var = stats[128 + c] * invN - mean * mean;
  float sc = g[c] * rsqrtf(var + 1e-5f);
  sshift[c] = sc;
  sshift[128 + c] = b[c] - mean * sc;
}

// ---- y1 <- relu(bn(y1)) in place, bf16 ----
__global__ __launch_bounds__(256) void apply_kernel(
    unsigned short* __restrict__ y, const float* __restrict__ ss, int total8) {
  int i = blockIdx.x * 256 + threadIdx.x;
  if (i >= total8) return;
  int cb = (i * 8) & 127;
  short8 u = ((short8*)y)[i];
#pragma unroll
  for (int j = 0; j < 8; ++j) {
    float f = bf2f((unsigned short)u[j]) * ss[cb + j] + ss[128 + cb + j];
    u[j] = (short)f2bf(fmaxf(f, 0.f));
  }
  ((short8*)y)[i] = u;
}

// ---- out <- relu(bn(y2) + x) in place (f32) ----
__global__ __launch_bounds__(256) void final_kernel(
    float* __restrict__ y2, const float* __restrict__ x,
    const float* __restrict__ ss, int total4) {
  int i = blockIdx.x * 256 + threadIdx.x;
  if (i >= total4) return;
  int cb = (i * 4) & 127;
  f32x4 v = ((const f32x4*)y2)[i];
  f32x4 xv = ((const f32x4*)x)[i];
#pragma unroll
  for (int j = 0; j < 4; ++j)
    v[j] = fmaxf(v[j] * ss[cb + j] + ss[128 + cb + j] + xv[j], 0.f);
  ((f32x4*)y2)[i] = v;
}

extern "C" void kernel_launch(void* const* d_in, const int* in_sizes, int n_in,
                              void* d_out, int out_size, void* d_ws, size_t ws_size,
                              hipStream_t stream) {
  const float* x  = (const float*)d_in[0];
  const int* nbr  = (const int*)d_in[1];
  const float* W1 = (const float*)d_in[2];
  const float* g1 = (const float*)d_in[3];
  const float* b1 = (const float*)d_in[4];
  const float* W2 = (const float*)d_in[5];
  const float* g2 = (const float*)d_in[6];
  const float* b2 = (const float*)d_in[7];
  float* out = (float*)d_out;

  const int N = in_sizes[0] / C_DIM;
  const int totalW = K_DIM * C_DIM * C_DIM;

  char* ws = (char*)d_ws;
  size_t off = 0;
  auto alloc = [&](size_t bytes) {
    void* p = ws + off;
    off = (off + bytes + 255) & ~(size_t)255;
    return p;
  };
  unsigned short* Wt1 = (unsigned short*)alloc((size_t)totalW * 2);
  unsigned short* Wt2 = (unsigned short*)alloc((size_t)totalW * 2);
  float* stats = (float*)alloc(512 * 4);   // [0:256) conv1, [256:512) conv2
  float* ss1   = (float*)alloc(256 * 4);
  float* ss2   = (float*)alloc(256 * 4);
  unsigned short* y1 = (unsigned short*)alloc((size_t)N * C_DIM * 2);
  unsigned short* xb = (unsigned short*)alloc((size_t)N * C_DIM * 2);
  const bool use_xb = (off <= ws_size);

  const int nblk = (N + 31) / 32;
  const float invN = 1.0f / (float)N;

  prep_kernel<<<(totalW + 255) / 256, 256, 0, stream>>>(W1, W2, Wt1, Wt2, stats, 512);

  if (use_xb) {
    int t4 = N * C_DIM / 4;
    cvt_x_kernel<<<(t4 + 255) / 256, 256, 0, stream>>>(x, xb, t4);
    conv_kernel<0, 0><<<nblk, 256, 0, stream>>>(xb, nbr, Wt1, y1, N);
  } else {
    conv_kernel<1, 0><<<nblk, 256, 0, stream>>>(x, nbr, Wt1, y1, N);
  }

  stats_kernel<0><<<256, 256, 0, stream>>>(y1, stats, N);
  finalize_kernel<<<1, 128, 0, stream>>>(stats, g1, b1, ss1, invN);

  {
    int t8 = N * C_DIM / 8;
    apply_kernel<<<(t8 + 255) / 256, 256, 0, stream>>>(y1, ss1, t8);
  }

  conv_kernel<0, 1><<<nblk, 256, 0, stream>>>(y1, nbr, Wt2, out, N);

  stats_kernel<1><<<256, 256, 0, stream>>>(out, stats + 256, N);
  finalize_kernel<<<1, 128, 0, stream>>>(stats + 256, g2, b2, ss2, invN);

  {
    int t4 = N * C_DIM / 4;
    final_kernel<<<(t4 + 255) / 256, 256, 0, stream>>>(out, x, ss2, t4);
  }
}

// Round 2
// 2044.160 us; speedup vs baseline: 1.3436x; 1.3436x over previous
//
#include <hip/hip_runtime.h>
#include <hip/hip_bf16.h>
#include <stdint.h>

#define C_DIM 128
#define K_DIM 27

typedef __attribute__((ext_vector_type(8))) short short8;
typedef __attribute__((ext_vector_type(4))) float f32x4;
typedef __attribute__((ext_vector_type(4))) unsigned short ushort4v;

__device__ __forceinline__ unsigned short f2bf(float f) {
  unsigned int u = __builtin_bit_cast(unsigned int, f);
  u += 0x7fffu + ((u >> 16) & 1u);   // round-to-nearest-even
  return (unsigned short)(u >> 16);
}
__device__ __forceinline__ float bf2f(unsigned short h) {
  unsigned int u = ((unsigned int)h) << 16;
  return __builtin_bit_cast(float, u);
}

// ---- transpose W1,W2 [k][ci][co] f32 -> [k][co][ci] bf16; zero stats ----
__global__ __launch_bounds__(256) void prep_kernel(
    const float* __restrict__ W1, const float* __restrict__ W2,
    unsigned short* __restrict__ Wt1, unsigned short* __restrict__ Wt2,
    float* __restrict__ stats, int stats_n) {
  int idx = blockIdx.x * 256 + threadIdx.x;
  const int total = K_DIM * C_DIM * C_DIM;
  if (idx < total) {
    int k = idx >> 14;          // / (128*128)
    int co = (idx >> 7) & 127;
    int ci = idx & 127;
    int src = (k * C_DIM + ci) * C_DIM + co;
    Wt1[idx] = f2bf(W1[src]);
    Wt2[idx] = f2bf(W2[src]);
  }
  if (idx < stats_n) stats[idx] = 0.f;
}

// ---- x f32 -> bf16 copy ----
__global__ __launch_bounds__(256) void cvt_x_kernel(
    const float* __restrict__ x, unsigned short* __restrict__ xb, int total4) {
  int i = blockIdx.x * 256 + threadIdx.x;
  if (i >= total4) return;
  f32x4 v = ((const f32x4*)x)[i];
  ushort4v u;
#pragma unroll
  for (int j = 0; j < 4; ++j) u[j] = f2bf(v[j]);
  ((ushort4v*)xb)[i] = u;
}

// ---- gathered GEMM: out[i] = sum_k src[nbr[i,k]] @ W[k] ----
// block = 256 thr (4 waves). Block computes 128 rows x 128 cols.
// Wave w owns rows [w*32, w*32+32) x all 128 cols: 2x8 tiles of 16x16x32.
// nbr indices for the block's 128 rows staged in LDS once (coalesced).
// No barriers in the k-loop; next-k indices prefetched.
template<int SRC_IS_F32, int OUT_IS_F32>
__global__ __launch_bounds__(256) void conv_kernel(
    const void* __restrict__ src_v, const int* __restrict__ nbr,
    const unsigned short* __restrict__ Wt, void* __restrict__ out_v, int N) {
  __shared__ int nbr_lds[128 * K_DIM];

  const int tid = threadIdx.x;
  const int wave = tid >> 6;
  const int lane = tid & 63;
  const int lr = lane & 15;   // A-row within 16-tile / B-col within 16-tile
  const int lg = lane >> 4;   // k-group 0..3
  const int row0 = blockIdx.x * 128;

  // cooperative, coalesced nbr preload: rows row0..row0+127 are contiguous
  {
    const int base = row0 * K_DIM;
    const int limit = N * K_DIM;
    for (int i = tid; i < 128 * K_DIM; i += 256) {
      int g = base + i;
      nbr_lds[i] = (g < limit) ? nbr[g] : 0;
    }
  }
  __syncthreads();

  const unsigned short* xb = (const unsigned short*)src_v;
  const float* xf = (const float*)src_v;

  f32x4 acc[2][8] = {};

  const int r0 = wave * 32 + lr;   // local row (A tile 0)
  const int r1 = r0 + 16;          // local row (A tile 1)
  const int lg8 = lg * 8;

  int i0 = nbr_lds[r0 * K_DIM];
  int i1 = nbr_lds[r1 * K_DIM];

  for (int k = 0; k < K_DIM; ++k) {
    const size_t ba0 = (size_t)i0 * C_DIM + lg8;
    const size_t ba1 = (size_t)i1 * C_DIM + lg8;
    short8 a0[4], a1[4];
    if (SRC_IS_F32) {
#pragma unroll
      for (int cs = 0; cs < 4; ++cs) {
        const f32x4* p0 = (const f32x4*)(xf + ba0 + cs * 32);
        const f32x4* p1 = (const f32x4*)(xf + ba1 + cs * 32);
        f32x4 v0 = p0[0], v1 = p0[1];
        f32x4 w0 = p1[0], w1 = p1[1];
#pragma unroll
        for (int j = 0; j < 4; ++j) {
          a0[cs][j]     = (short)f2bf(v0[j]);
          a0[cs][j + 4] = (short)f2bf(v1[j]);
          a1[cs][j]     = (short)f2bf(w0[j]);
          a1[cs][j + 4] = (short)f2bf(w1[j]);
        }
      }
    } else {
#pragma unroll
      for (int cs = 0; cs < 4; ++cs) {
        a0[cs] = *(const short8*)(xb + ba0 + (size_t)cs * 32);
        a1[cs] = *(const short8*)(xb + ba1 + (size_t)cs * 32);
      }
    }
    // prefetch next k's gather indices (breaks the dependent chain)
    if (k + 1 < K_DIM) {
      i0 = nbr_lds[r0 * K_DIM + k + 1];
      i1 = nbr_lds[r1 * K_DIM + k + 1];
    }
    const unsigned short* wk =
        Wt + ((size_t)k << 14) + (size_t)lr * C_DIM + lg8;
#pragma unroll
    for (int cs = 0; cs < 4; ++cs) {
#pragma unroll
      for (int ct = 0; ct < 8; ++ct) {
        short8 b = *(const short8*)(wk + (size_t)ct * 16 * C_DIM + cs * 32);
        acc[0][ct] = __builtin_amdgcn_mfma_f32_16x16x32_bf16(a0[cs], b, acc[0][ct], 0, 0, 0);
        acc[1][ct] = __builtin_amdgcn_mfma_f32_16x16x32_bf16(a1[cs], b, acc[1][ct], 0, 0, 0);
      }
    }
  }

  // C/D layout: col = lane&15, row = (lane>>4)*4 + reg  [m89-verified]
  const int wrow = row0 + wave * 32;
#pragma unroll
  for (int r = 0; r < 2; ++r) {
#pragma unroll
    for (int j = 0; j < 4; ++j) {
      int row = wrow + r * 16 + lg * 4 + j;
      if (row >= N) continue;
#pragma unroll
      for (int ct = 0; ct < 8; ++ct) {
        int col = ct * 16 + lr;
        if (OUT_IS_F32)
          ((float*)out_v)[(size_t)row * C_DIM + col] = acc[r][ct][j];
        else
          ((unsigned short*)out_v)[(size_t)row * C_DIM + col] = f2bf(acc[r][ct][j]);
      }
    }
  }
}

// ---- per-channel sum / sumsq ----
template<int SRC_IS_F32>
__global__ __launch_bounds__(256) void stats_kernel(
    const void* __restrict__ y_v, float* __restrict__ stats, int N) {
  const int tid = threadIdx.x;
  const int c = tid & 127;
  const int half = tid >> 7;
  const float* yf = (const float*)y_v;
  const unsigned short* yb = (const unsigned short*)y_v;
  float s = 0.f, ss = 0.f;
  for (int row = blockIdx.x * 2 + half; row < N; row += gridDim.x * 2) {
    float v = SRC_IS_F32 ? yf[(size_t)row * C_DIM + c]
                         : bf2f(yb[(size_t)row * C_DIM + c]);
    s += v;
    ss += v * v;
  }
  __shared__ float sh_s[128], sh_ss[128];
  if (half == 1) { sh_s[c] = s; sh_ss[c] = ss; }
  __syncthreads();
  if (half == 0) {
    atomicAdd(&stats[c], s + sh_s[c]);
    atomicAdd(&stats[128 + c], ss + sh_ss[c]);
  }
}

// ---- stats -> scale/shift ----
__global__ void finalize_kernel(const float* __restrict__ stats,
                                const float* __restrict__ g,
                                const float* __restrict__ b,
                                float* __restrict__ sshift, float invN) {
  int c = threadIdx.x;  // blockDim = 128
  float mean = stats[c] * invN;
  float var = stats[128 + c] * invN - mean * mean;
  float sc = g[c] * rsqrtf(var + 1e-5f);
  sshift[c] = sc;
  sshift[128 + c] = b[c] - mean * sc;
}

// ---- y1 <- relu(bn(y1)) in place, bf16 ----
__global__ __launch_bounds__(256) void apply_kernel(
    unsigned short* __restrict__ y, const float* __restrict__ ss, int total8) {
  int i = blockIdx.x * 256 + threadIdx.x;
  if (i >= total8) return;
  int cb = (i * 8) & 127;
  short8 u = ((short8*)y)[i];
#pragma unroll
  for (int j = 0; j < 8; ++j) {
    float f = bf2f((unsigned short)u[j]) * ss[cb + j] + ss[128 + cb + j];
    u[j] = (short)f2bf(fmaxf(f, 0.f));
  }
  ((short8*)y)[i] = u;
}

// ---- out <- relu(bn(y2) + x) in place (f32) ----
__global__ __launch_bounds__(256) void final_kernel(
    float* __restrict__ y2, const float* __restrict__ x,
    const float* __restrict__ ss, int total4) {
  int i = blockIdx.x * 256 + threadIdx.x;
  if (i >= total4) return;
  int cb = (i * 4) & 127;
  f32x4 v = ((const f32x4*)y2)[i];
  f32x4 xv = ((const f32x4*)x)[i];
#pragma unroll
  for (int j = 0; j < 4; ++j)
    v[j] = fmaxf(v[j] * ss[cb + j] + ss[128 + cb + j] + xv[j], 0.f);
  ((f32x4*)y2)[i] = v;
}

extern "C" void kernel_launch(void* const* d_in, const int* in_sizes, int n_in,
                              void* d_out, int out_size, void* d_ws, size_t ws_size,
                              hipStream_t stream) {
  const float* x  = (const float*)d_in[0];
  const int* nbr  = (const int*)d_in[1];
  const float* W1 = (const float*)d_in[2];
  const float* g1 = (const float*)d_in[3];
  const float* b1 = (const float*)d_in[4];
  const float* W2 = (const float*)d_in[5];
  const float* g2 = (const float*)d_in[6];
  const float* b2 = (const float*)d_in[7];
  float* out = (float*)d_out;

  const int N = in_sizes[0] / C_DIM;
  const int totalW = K_DIM * C_DIM * C_DIM;

  char* ws = (char*)d_ws;
  size_t off = 0;
  auto alloc = [&](size_t bytes) {
    void* p = ws + off;
    off = (off + bytes + 255) & ~(size_t)255;
    return p;
  };
  unsigned short* Wt1 = (unsigned short*)alloc((size_t)totalW * 2);
  unsigned short* Wt2 = (unsigned short*)alloc((size_t)totalW * 2);
  float* stats = (float*)alloc(512 * 4);   // [0:256) conv1, [256:512) conv2
  float* ss1   = (float*)alloc(256 * 4);
  float* ss2   = (float*)alloc(256 * 4);
  unsigned short* y1 = (unsigned short*)alloc((size_t)N * C_DIM * 2);
  unsigned short* xb = (unsigned short*)alloc((size_t)N * C_DIM * 2);
  const bool use_xb = (off <= ws_size);

  const int nblk = (N + 127) / 128;
  const float invN = 1.0f / (float)N;

  prep_kernel<<<(totalW + 255) / 256, 256, 0, stream>>>(W1, W2, Wt1, Wt2, stats, 512);

  if (use_xb) {
    int t4 = N * C_DIM / 4;
    cvt_x_kernel<<<(t4 + 255) / 256, 256, 0, stream>>>(x, xb, t4);
    conv_kernel<0, 0><<<nblk, 256, 0, stream>>>(xb, nbr, Wt1, y1, N);
  } else {
    conv_kernel<1, 0><<<nblk, 256, 0, stream>>>(x, nbr, Wt1, y1, N);
  }

  stats_kernel<0><<<256, 256, 0, stream>>>(y1, stats, N);
  finalize_kernel<<<1, 128, 0, stream>>>(stats, g1, b1, ss1, invN);

  {
    int t8 = N * C_DIM / 8;
    apply_kernel<<<(t8 + 255) / 256, 256, 0, stream>>>(y1, ss1, t8);
  }

  conv_kernel<0, 1><<<nblk, 256, 0, stream>>>(y1, nbr, Wt2, out, N);

  stats_kernel<1><<<256, 256, 0, stream>>>(out, stats + 256, N);
  finalize_kernel<<<1, 128, 0, stream>>>(stats + 256, g2, b2, ss2, invN);

  {
    int t4 = N * C_DIM / 4;
    final_kernel<<<(t4 + 255) / 256, 256, 0, stream>>>(out, x, ss2, t4);
  }
}

// Round 3
// 1706.963 us; speedup vs baseline: 1.6090x; 1.1975x over previous
//
#include <hip/hip_runtime.h>
#include <hip/hip_bf16.h>
#include <stdint.h>

#define C_DIM 128
#define K_DIM 27

typedef __attribute__((ext_vector_type(8))) short short8;
typedef __attribute__((ext_vector_type(4))) float f32x4;
typedef __attribute__((ext_vector_type(4))) unsigned short ushort4v;

__device__ __forceinline__ unsigned short f2bf(float f) {
  unsigned int u = __builtin_bit_cast(unsigned int, f);
  u += 0x7fffu + ((u >> 16) & 1u);   // round-to-nearest-even
  return (unsigned short)(u >> 16);
}
__device__ __forceinline__ float bf2f(unsigned short h) {
  unsigned int u = ((unsigned int)h) << 16;
  return __builtin_bit_cast(float, u);
}

__device__ __forceinline__ void async_copy16(const void* gsrc, void* ldst) {
  __builtin_amdgcn_global_load_lds(
      (const __attribute__((address_space(1))) unsigned int*)gsrc,
      (__attribute__((address_space(3))) unsigned int*)ldst, 16, 0, 0);
}

// ---- W [k][ci][co] f32 -> swizzled bf16 [k][co][granule g^(co&7)][8]; zero stats ----
__global__ __launch_bounds__(256) void prep_kernel(
    const float* __restrict__ W1, const float* __restrict__ W2,
    unsigned short* __restrict__ Wt1, unsigned short* __restrict__ Wt2,
    float* __restrict__ stats, int stats_n) {
  int idx = blockIdx.x * 256 + threadIdx.x;
  const int total = K_DIM * C_DIM * C_DIM;
  if (idx < total) {
    int k = idx >> 14;
    int r = idx & 16383;
    int co = r >> 7;
    int gpos = (r >> 3) & 15;
    int e = r & 7;
    int gg = gpos ^ (co & 7);     // logical granule
    int ci = gg * 8 + e;
    int src = (k * C_DIM + ci) * C_DIM + co;
    Wt1[idx] = f2bf(W1[src]);
    Wt2[idx] = f2bf(W2[src]);
  }
  if (idx < stats_n) stats[idx] = 0.f;
}

// ---- x f32 -> bf16 copy ----
__global__ __launch_bounds__(256) void cvt_x_kernel(
    const float* __restrict__ x, unsigned short* __restrict__ xb, int total4) {
  int i = blockIdx.x * 256 + threadIdx.x;
  if (i >= total4) return;
  f32x4 v = ((const f32x4*)x)[i];
  ushort4v u;
#pragma unroll
  for (int j = 0; j < 4; ++j) u[j] = f2bf(v[j]);
  ((ushort4v*)xb)[i] = u;
}

// ---- helpers for the conv kernel ----
__device__ __forceinline__ void stage_w(const unsigned short* Wt_k,
                                        unsigned short* buf, int wave, int lane) {
  const unsigned short* src = Wt_k + wave * 4096 + lane * 8;
  unsigned short* dst = buf + wave * 4096;      // wave-uniform; HW adds lane*16B
#pragma unroll
  for (int c = 0; c < 8; ++c)
    async_copy16(src + c * 512, dst + c * 512);
}

__device__ __forceinline__ void load_idx(int (&idx)[4], const int* __restrict__ nbr,
                                         const int (&nb_off)[4], int k) {
#pragma unroll
  for (int rt = 0; rt < 4; ++rt) idx[rt] = nbr[nb_off[rt] + k];
}

__device__ __forceinline__ void load_a(short8 (&a)[4][4], const int (&idx)[4],
                                       const unsigned short* __restrict__ xb, int lg) {
#pragma unroll
  for (int rt = 0; rt < 4; ++rt) {
    const unsigned short* p = xb + (size_t)idx[rt] * C_DIM + lg * 8;
#pragma unroll
    for (int cs = 0; cs < 4; ++cs)
      a[rt][cs] = *(const short8*)(p + cs * 32);
  }
}

__device__ __forceinline__ void compute_k(
    const unsigned short* wb, short8 (&a)[4][4], f32x4 (&acc)[4][4],
    int lr, int lg, int cg) {
#pragma unroll
  for (int cs = 0; cs < 4; ++cs) {
#pragma unroll
    for (int ct = 0; ct < 4; ++ct) {
      const int co = cg * 64 + ct * 16 + lr;
      const int gg = cs * 4 + lg;
      short8 b = *(const short8*)(wb + co * 128 + ((gg ^ (co & 7)) << 3));
#pragma unroll
      for (int rt = 0; rt < 4; ++rt)
        acc[rt][ct] = __builtin_amdgcn_mfma_f32_16x16x32_bf16(a[rt][cs], b, acc[rt][ct], 0, 0, 0);
    }
  }
}

// ---- gathered GEMM: out[i] = sum_k src[nbr[i,k]] @ W[k], fused BN stats ----
// 256 thr (4 waves), block tile 128 rows x 128 cols; wave (rg,cg) owns 64x64.
// W[k] double-buffered in LDS via global_load_lds (pre-swizzled source);
// A fragments double-buffered in registers; nbr prefetched 1 k ahead.
template<int OUT_IS_F32>
__global__ __launch_bounds__(256, 2) void conv_kernel(
    const unsigned short* __restrict__ xb, const int* __restrict__ nbr,
    const unsigned short* __restrict__ Wt, void* __restrict__ out_v,
    float* __restrict__ stats, int N) {
  __shared__ __align__(16) unsigned short wbuf[2][16384];  // 2 x 32KB
  __shared__ float s_sum[C_DIM], s_ssum[C_DIM];

  const int tid = threadIdx.x;
  const int wave = tid >> 6, lane = tid & 63;
  const int lr = lane & 15, lg = lane >> 4;
  const int rg = wave >> 1, cg = wave & 1;
  const int row0 = blockIdx.x * 128;

  if (tid < C_DIM) { s_sum[tid] = 0.f; s_ssum[tid] = 0.f; }

  int nb_off[4];
#pragma unroll
  for (int rt = 0; rt < 4; ++rt) {
    int rr = row0 + rg * 64 + rt * 16 + lr;
    nb_off[rt] = (rr < N ? rr : N - 1) * K_DIM;
  }

  stage_w(Wt, wbuf[0], wave, lane);

  int idxC[4], idxN[4];
  load_idx(idxC, nbr, nb_off, 0);
  short8 a0[4][4], a1[4][4];
  load_a(a0, idxC, xb, lg);
  load_idx(idxN, nbr, nb_off, 1);

  f32x4 acc[4][4] = {};

  __syncthreads();   // W[0] staged; stats zeroed

  for (int k = 0; k < K_DIM; k += 2) {
    // even sub-iter: compute k from a0 / wbuf[0]
    if (k + 1 < K_DIM) {
      stage_w(Wt + (size_t)(k + 1) * 16384, wbuf[1], wave, lane);
      load_a(a1, idxN, xb, lg);
    }
    if (k + 2 < K_DIM) load_idx(idxN, nbr, nb_off, k + 2);
    compute_k(wbuf[0], a0, acc, lr, lg, cg);
    __syncthreads();
    if (k + 1 >= K_DIM) break;
    // odd sub-iter: compute k+1 from a1 / wbuf[1]
    if (k + 2 < K_DIM) {
      stage_w(Wt + (size_t)(k + 2) * 16384, wbuf[0], wave, lane);
      load_a(a0, idxN, xb, lg);
    }
    if (k + 3 < K_DIM) load_idx(idxN, nbr, nb_off, k + 3);
    compute_k(wbuf[1], a1, acc, lr, lg, cg);
    __syncthreads();
  }

  // ---- epilogue: store + fused per-channel sum/sumsq ----
  const int wrow = row0 + rg * 64;
  float ps[4] = {0.f, 0.f, 0.f, 0.f}, pss[4] = {0.f, 0.f, 0.f, 0.f};
#pragma unroll
  for (int rt = 0; rt < 4; ++rt) {
#pragma unroll
    for (int j = 0; j < 4; ++j) {
      int row = wrow + rt * 16 + lg * 4 + j;
      bool ok = row < N;
#pragma unroll
      for (int ct = 0; ct < 4; ++ct) {
        float v = acc[rt][ct][j];
        if (ok) {
          int col = cg * 64 + ct * 16 + lr;
          if (OUT_IS_F32)
            ((float*)out_v)[(size_t)row * C_DIM + col] = v;
          else
            ((unsigned short*)out_v)[(size_t)row * C_DIM + col] = f2bf(v);
          ps[ct] += v;
          pss[ct] += v * v;
        }
      }
    }
  }
#pragma unroll
  for (int ct = 0; ct < 4; ++ct) {
    // lanes sharing a col differ only in lg (lane bits 4,5)
    ps[ct]  += __shfl_xor(ps[ct], 16, 64);
    ps[ct]  += __shfl_xor(ps[ct], 32, 64);
    pss[ct] += __shfl_xor(pss[ct], 16, 64);
    pss[ct] += __shfl_xor(pss[ct], 32, 64);
    if (lg == 0) {
      int col = cg * 64 + ct * 16 + lr;
      atomicAdd(&s_sum[col], ps[ct]);
      atomicAdd(&s_ssum[col], pss[ct]);
    }
  }
  __syncthreads();
  if (tid < C_DIM) {
    atomicAdd(&stats[tid], s_sum[tid]);
    atomicAdd(&stats[C_DIM + tid], s_ssum[tid]);
  }
}

// ---- stats -> scale/shift ----
__global__ void finalize_kernel(const float* __restrict__ stats,
                                const float* __restrict__ g,
                                const float* __restrict__ b,
                                float* __restrict__ sshift, float invN) {
  int c = threadIdx.x;  // blockDim = 128
  float mean = stats[c] * invN;
  float var = stats[128 + c] * invN - mean * mean;
  float sc = g[c] * rsqrtf(var + 1e-5f);
  sshift[c] = sc;
  sshift[128 + c] = b[c] - mean * sc;
}

// ---- y1 <- relu(bn(y1)) in place, bf16 ----
__global__ __launch_bounds__(256) void apply_kernel(
    unsigned short* __restrict__ y, const float* __restrict__ ss, int total8) {
  int i = blockIdx.x * 256 + threadIdx.x;
  if (i >= total8) return;
  int cb = (i * 8) & 127;
  short8 u = ((short8*)y)[i];
#pragma unroll
  for (int j = 0; j < 8; ++j) {
    float f = bf2f((unsigned short)u[j]) * ss[cb + j] + ss[128 + cb + j];
    u[j] = (short)f2bf(fmaxf(f, 0.f));
  }
  ((short8*)y)[i] = u;
}

// ---- out <- relu(bn(y2) + x) in place (f32) ----
__global__ __launch_bounds__(256) void final_kernel(
    float* __restrict__ y2, const float* __restrict__ x,
    const float* __restrict__ ss, int total4) {
  int i = blockIdx.x * 256 + threadIdx.x;
  if (i >= total4) return;
  int cb = (i * 4) & 127;
  f32x4 v = ((const f32x4*)y2)[i];
  f32x4 xv = ((const f32x4*)x)[i];
#pragma unroll
  for (int j = 0; j < 4; ++j)
    v[j] = fmaxf(v[j] * ss[cb + j] + ss[128 + cb + j] + xv[j], 0.f);
  ((f32x4*)y2)[i] = v;
}

extern "C" void kernel_launch(void* const* d_in, const int* in_sizes, int n_in,
                              void* d_out, int out_size, void* d_ws, size_t ws_size,
                              hipStream_t stream) {
  const float* x  = (const float*)d_in[0];
  const int* nbr  = (const int*)d_in[1];
  const float* W1 = (const float*)d_in[2];
  const float* g1 = (const float*)d_in[3];
  const float* b1 = (const float*)d_in[4];
  const float* W2 = (const float*)d_in[5];
  const float* g2 = (const float*)d_in[6];
  const float* b2 = (const float*)d_in[7];
  float* out = (float*)d_out;

  const int N = in_sizes[0] / C_DIM;
  const int totalW = K_DIM * C_DIM * C_DIM;

  char* ws = (char*)d_ws;
  size_t off = 0;
  auto alloc = [&](size_t bytes) {
    void* p = ws + off;
    off = (off + bytes + 255) & ~(size_t)255;
    return p;
  };
  unsigned short* Wt1 = (unsigned short*)alloc((size_t)totalW * 2);
  unsigned short* Wt2 = (unsigned short*)alloc((size_t)totalW * 2);
  float* stats = (float*)alloc(512 * 4);   // [0:256) conv1, [256:512) conv2
  float* ss1   = (float*)alloc(256 * 4);
  float* ss2   = (float*)alloc(256 * 4);
  unsigned short* y1 = (unsigned short*)alloc((size_t)N * C_DIM * 2);
  unsigned short* xb_ws = (unsigned short*)alloc((size_t)N * C_DIM * 2);
  // fall back to d_out's storage for the bf16 x copy if ws is too small
  // (conv2 overwrites d_out only after conv1 has consumed xb)
  unsigned short* xb = (off <= ws_size) ? xb_ws : (unsigned short*)d_out;

  const int nblk = (N + 127) / 128;
  const float invN = 1.0f / (float)N;

  prep_kernel<<<(totalW + 255) / 256, 256, 0, stream>>>(W1, W2, Wt1, Wt2, stats, 512);

  {
    int t4 = N * C_DIM / 4;
    cvt_x_kernel<<<(t4 + 255) / 256, 256, 0, stream>>>(x, xb, t4);
  }

  conv_kernel<0><<<nblk, 256, 0, stream>>>(xb, nbr, Wt1, y1, stats, N);
  finalize_kernel<<<1, 128, 0, stream>>>(stats, g1, b1, ss1, invN);

  {
    int t8 = N * C_DIM / 8;
    apply_kernel<<<(t8 + 255) / 256, 256, 0, stream>>>(y1, ss1, t8);
  }

  conv_kernel<1><<<nblk, 256, 0, stream>>>(y1, nbr, Wt2, out, stats + 256, N);
  finalize_kernel<<<1, 128, 0, stream>>>(stats + 256, g2, b2, ss2, invN);

  {
    int t4 = N * C_DIM / 4;
    final_kernel<<<(t4 + 255) / 256, 256, 0, stream>>>(out, x, ss2, t4);
  }
}